// Round 1
// baseline (376.980 us; speedup 1.0000x reference)
//
#include <hip/hip_runtime.h>
#include <math.h>

// S4D layer: B=8, H=512, L=2048, N=64.
// Chunked state-space scan, T=64 per chunk, NC=32 chunks.
// One wave per (b,h); 4 waves per block (4 batches) share per-h LDS tables.

#define TCH 64   // chunk length
#define NST 64   // state size N (== wavefront size)

__global__ void s4d_chunked_kernel(
    const float* __restrict__ u,
    const float* __restrict__ A_re,
    const float* __restrict__ A_im,
    const float* __restrict__ C,
    const float* __restrict__ Dp,
    const float* __restrict__ log_step,
    float* __restrict__ out,
    int B, int H, int L)
{
    const int h    = blockIdx.x;
    const int wv   = threadIdx.x >> 6;        // wave id within block (0..3)
    const int lane = threadIdx.x & 63;
    const int b    = blockIdx.y * 4 + wv;     // batch index for this wave

    __shared__ float Mre[TCH][NST + 1];       // M[j][n] = Re/Im( c_n * r_n^(j+1) ), padded stride 65
    __shared__ float Mim[TCH][NST + 1];
    __shared__ float Kl[TCH];                 // K[i] = Re sum_n c_n r_n^i, i in [0,64)

    // ---- per-lane (n = lane) setup: r = exp(dt*A), c = Cc*(exp(dt*A)-1)/A ----
    const int n = lane;
    const float are = fminf(A_re[h * NST + n], -1e-4f);
    const float aim = A_im[h * NST + n];
    const float dt  = expf(log_step[h]);
    const float dre = dt * are;
    const float dim = dt * aim;
    const float er  = expf(dre);
    float sn_, cs_;
    sincosf(dim, &sn_, &cs_);
    const float rre = er * cs_;               // r = exp(dtA)
    const float rim = er * sn_;
    // 1/A = conj(A)/|A|^2
    const float den = are * are + aim * aim;
    const float ire = are / den;
    const float iim = -aim / den;
    // t = (exp(dtA)-1)/A
    const float e1re = rre - 1.0f;
    const float e1im = rim;
    const float tre = e1re * ire - e1im * iim;
    const float tim = e1re * iim + e1im * ire;
    // c = Cc * t
    const float c0re = C[(h * NST + n) * 2 + 0];
    const float c0im = C[(h * NST + n) * 2 + 1];
    const float cre = c0re * tre - c0im * tim;
    const float cim = c0re * tim + c0im * tre;

    // ---- build M and K tables cooperatively (wave wv handles j in [16*wv, 16*wv+16)) ----
    // q = r^16
    float qre = rre, qim = rim;
    #pragma unroll
    for (int t = 0; t < 4; ++t) {
        float nr = qre * qre - qim * qim;
        qim = 2.0f * qre * qim;
        qre = nr;
    }
    // wpow = r^(16*wv)
    float wre = 1.0f, wim = 0.0f;
    for (int t = 0; t < wv; ++t) {
        float nr = wre * qre - wim * qim;
        wim = wre * qim + wim * qre;
        wre = nr;
    }
    // mk = c * r^(16*wv)
    float mre = cre * wre - cim * wim;
    float mim = cre * wim + cim * wre;
    #pragma unroll
    for (int jj = 0; jj < 16; ++jj) {
        const int j = wv * 16 + jj;
        // K[j] = Re sum_n c r^j  (mk currently == c*r^j)
        float red = mre;
        #pragma unroll
        for (int off = 32; off; off >>= 1) red += __shfl_xor(red, off);
        if (lane == 0) Kl[j] = red;
        // mk *= r  -> c*r^(j+1)
        float nr = mre * rre - mim * rim;
        mim = mre * rim + mim * rre;
        mre = nr;
        Mre[j][lane] = mre;
        Mim[j][lane] = mim;
    }
    __syncthreads();

    // ---- main chunked scan over the sequence ----
    const float Dh = Dp[h];
    const size_t base = ((size_t)b * H + h) * (size_t)L;
    float sre = 0.0f, sim = 0.0f;             // state s_n (n = lane), through position p-1
    const int NCH = L / TCH;

    for (int k = 0; k < NCH; ++k) {
        const int p = k * TCH;
        const float ur = u[base + p + lane];  // lane j holds u[p+j]

        // cross term: y[j] = sum_n ( Mre[j][n]*s_re[n] - Mim[j][n]*s_im[n] )
        float y = 0.0f;
        #pragma unroll 8
        for (int nn = 0; nn < NST; ++nn) {
            const float sr = __shfl(sre, nn);
            const float si = __shfl(sim, nn);
            y = fmaf(Mre[lane][nn], sr, y);
            y = fmaf(-Mim[lane][nn], si, y);
        }

        // local causal conv + state recurrence, fused over source position t
        #pragma unroll 8
        for (int t = 0; t < TCH; ++t) {
            const float ub = __shfl(ur, t);           // u[p+t]
            const float kv = Kl[(lane - t) & 63];     // K[j - t]
            const float contrib = kv * ub;
            y += (t <= lane) ? contrib : 0.0f;
            // s = r*s + u[p+t]
            const float nr = fmaf(rre, sre, fmaf(-rim, sim, ub));
            sim = fmaf(rre, sim, rim * sre);
            sre = nr;
        }

        out[base + p + lane] = y + Dh * ur;
    }
}

extern "C" void kernel_launch(void* const* d_in, const int* in_sizes, int n_in,
                              void* d_out, int out_size, void* d_ws, size_t ws_size,
                              hipStream_t stream) {
    const float* u        = (const float*)d_in[0];
    const float* A_re     = (const float*)d_in[1];
    const float* A_im     = (const float*)d_in[2];
    const float* C        = (const float*)d_in[3];
    const float* Dp       = (const float*)d_in[4];
    const float* log_step = (const float*)d_in[5];
    float* out = (float*)d_out;

    const int H = in_sizes[4];                 // D has H elements (512)
    const int N = in_sizes[1] / H;             // 64
    const int BL = in_sizes[0] / H;            // B*L
    const int L = 2048;                        // fixed by problem
    const int B = BL / L;                      // 8
    (void)N; (void)d_ws; (void)ws_size; (void)out_size; (void)n_in;

    dim3 grid(H, B / 4);
    dim3 block(256);
    hipLaunchKernelGGL(s4d_chunked_kernel, grid, block, 0, stream,
                       u, A_re, A_im, C, Dp, log_step, out, B, H, L);
}

// Round 2
// 49.765 us; speedup vs baseline: 7.5752x; 7.5752x over previous
//
#include <hip/hip_runtime.h>
#include <math.h>

// S4D layer B=8,H=512,L=2048,N=64 via chunked state-space + MFMA.
// Per block (one h): build tables, then per b: phaseA GEMM -> scan -> phaseC GEMM.

typedef short bf16x8 __attribute__((ext_vector_type(8)));
typedef float f32x4  __attribute__((ext_vector_type(4)));

#define NCHK 32
#define USTR 68   // padded stride for [32][68] f32 arrays (balanced b128 bank groups)
#define ESTR 72   // padded stride for bf16 E table rows

__device__ __forceinline__ short f2bf(float x){
    unsigned u = __float_as_uint(x);
    u += 0x7FFFu + ((u >> 16) & 1u);          // RNE
    return (short)(u >> 16);
}
__device__ __forceinline__ float bf2f(short h){
    return __uint_as_float(((unsigned)(unsigned short)h) << 16);
}

__global__ void __launch_bounds__(256) s4d_mfma(
    const float* __restrict__ u_g, const float* __restrict__ A_re,
    const float* __restrict__ A_im, const float* __restrict__ Cg,
    const float* __restrict__ Dp, const float* __restrict__ log_step,
    float* __restrict__ out, int B, int H, int L)
{
    const int h    = blockIdx.x;
    const int tid  = threadIdx.x;
    const int wv   = tid >> 6;
    const int lane = tid & 63;
    const int l15  = lane & 15;
    const int oct  = lane >> 4;

    __shared__ __align__(16) float u_s[2][NCHK][USTR];  // [buf][chunk][t]
    __shared__ __align__(16) float w_s[2][NCHK][USTR];  // [re/im][k][n]
    __shared__ __align__(16) float S_s[2][NCHK][USTR];  // [re/im][k][n] = S[k-1]
    __shared__ __align__(16) short E_s[2][65][ESTR];    // [re/-im][p][n] = c_n r_n^p (bf16)
    __shared__ float K_s[64];

    const float dt = expf(log_step[h]);

    // ---- per-lane (n = lane) params ----
    const float are = fminf(A_re[h*64 + lane], -1e-4f);
    const float aim = A_im[h*64 + lane];
    const float dre = dt * are, dim = dt * aim;
    float sn_, cs_;
    const float er = expf(dre);
    sincosf(dim, &sn_, &cs_);
    const float rre = er * cs_, rim = er * sn_;          // r = exp(dtA)
    const float den = are*are + aim*aim;
    const float ir  = are/den, ii = -aim/den;            // 1/A
    const float c0r = Cg[(h*64+lane)*2 + 0];
    const float c0i = Cg[(h*64+lane)*2 + 1];
    const float e1r = rre - 1.0f, e1i = rim;             // exp(dtA)-1
    const float ttr = e1r*ir - e1i*ii;
    const float tti = e1r*ii + e1i*ir;
    const float cre = c0r*ttr - c0i*tti;                 // c = Cc*(exp(dtA)-1)/A
    const float cim = c0r*tti + c0i*ttr;

    // ---- stage u(b=0) ----
    {
        const float* up = u_g + (size_t)h * (size_t)L;
        float4 a0 = *(const float4*)(up + tid*8);
        float4 a1 = *(const float4*)(up + tid*8 + 4);
        const int ch = (tid*8) >> 6, t0 = (tid*8) & 63;
        *(float4*)&u_s[0][ch][t0]   = a0;
        *(float4*)&u_s[0][ch][t0+4] = a1;
    }

    // ---- build E[p][n] = c_n r_n^p (p=0..64) and K[d] = Re sum_n c r^d ----
    {
        float qre = rre, qim = rim;                      // -> r^16
        #pragma unroll
        for (int i=0;i<4;++i){ float t2 = qre*qre - qim*qim; qim = 2.0f*qre*qim; qre = t2; }
        float wre = 1.0f, wim = 0.0f;                    // -> r^(16*wv)
        for (int i=0;i<wv;++i){ float t2 = wre*qre - wim*qim; wim = wre*qim + wim*qre; wre = t2; }
        float mre = cre*wre - cim*wim;
        float mim = cre*wim + cim*wre;                   // c * r^(16wv)
        #pragma unroll
        for (int jj=0;jj<16;++jj){
            const int p = wv*16 + jj;
            float red = mre;
            #pragma unroll
            for (int off=32; off; off>>=1) red += __shfl_xor(red, off);
            if (lane == 0) K_s[p] = red;
            E_s[0][p][lane] = f2bf(mre);
            E_s[1][p][lane] = f2bf(-mim);                // bake negation for Re(M*S)
            const float t2 = mre*rre - mim*rim;
            mim = mre*rim + mim*rre; mre = t2;
        }
        if (wv == 3){ E_s[0][64][lane] = f2bf(mre); E_s[1][64][lane] = f2bf(-mim); }
    }
    __syncthreads();

    // ---- register fragments (A-operands), tile row = wv ----
    bf16x8 Wre[2], Wim[2], Mre[2], Mni[2], Tf[2];
    {
        const int nw = wv*16 + l15;                      // W row n (phase A)
        const float aw = fminf(A_re[h*64+nw], -1e-4f);
        const float bw = A_im[h*64+nw];
        const float dr = dt*aw, di = dt*bw;
        float s1, c1;
        const float e1 = expf(dr); sincosf(di, &s1, &c1);
        const float rwr = e1*c1, rwi = e1*s1;            // r_nw
        #pragma unroll
        for (int kh=0; kh<2; ++kh){
            const int elo = 63 - (kh*32 + oct*8) - 7;    // exponent at i=7
            float s2, c2;
            const float e2 = expf(dr*(float)elo); sincosf(di*(float)elo, &s2, &c2);
            float vr = e2*c2, vi = e2*s2;                // r^elo
            Wre[kh][7] = f2bf(vr); Wim[kh][7] = f2bf(vi);
            #pragma unroll
            for (int i=6;i>=0;--i){                      // exponent +1 per step
                const float t2 = vr*rwr - vi*rwi;
                vi = vr*rwi + vi*rwr; vr = t2;
                Wre[kh][i] = f2bf(vr); Wim[kh][i] = f2bf(vi);
            }
        }
        const int jp1 = wv*16 + l15 + 1;                 // M[j][n] = E[j+1][n]
        #pragma unroll
        for (int kh=0; kh<2; ++kh){
            Mre[kh] = *(const bf16x8*)&E_s[0][jp1][kh*32 + oct*8];
            Mni[kh] = *(const bf16x8*)&E_s[1][jp1][kh*32 + oct*8];
            #pragma unroll
            for (int i=0;i<8;++i){
                const int t = kh*32 + oct*8 + i;
                const int d = (wv*16 + l15) - t;         // T[j][t] = K[j-t] (t<=j)
                Tf[kh][i] = (d >= 0) ? f2bf(K_s[d]) : (short)0;
            }
        }
    }
    float rhor = 0.0f, rhoi = 0.0f;
    if (wv == 0){                                        // rho = r^64 (scan wave)
        float s3, c3;
        const float e3 = expf(dre * 64.0f); sincosf(dim * 64.0f, &s3, &c3);
        rhor = e3*c3; rhoi = e3*s3;
    }
    const float Dh = Dp[h];

    // ---- per-batch loop ----
    for (int b=0; b<B; ++b){
        const int buf = b & 1;
        const size_t obase = ((size_t)b*H + h) * (size_t)L;
        float4 p0 = {0,0,0,0}, p1 = {0,0,0,0};
        const bool pf = (b+1 < B);
        if (pf){                                         // prefetch next u
            const float* up = u_g + ((size_t)(b+1)*H + h) * (size_t)L;
            p0 = *(const float4*)(up + tid*8);
            p1 = *(const float4*)(up + tid*8 + 4);
        }
        // U B-fragments (hi/lo split), shared by phases A and C
        bf16x8 Uh[2][2], Ul[2][2];
        #pragma unroll
        for (int ct=0; ct<2; ++ct){
            const int ch = ct*16 + l15;
            #pragma unroll
            for (int kh=0; kh<2; ++kh){
                const float4 x0 = *(const float4*)&u_s[buf][ch][kh*32 + oct*8];
                const float4 x1 = *(const float4*)&u_s[buf][ch][kh*32 + oct*8 + 4];
                const float f[8] = {x0.x,x0.y,x0.z,x0.w,x1.x,x1.y,x1.z,x1.w};
                #pragma unroll
                for (int i=0;i<8;++i){
                    const short hi = f2bf(f[i]);
                    Uh[ct][kh][i] = hi;
                    Ul[ct][kh][i] = f2bf(f[i] - bf2f(hi));
                }
            }
        }
        // phase A: w[n,k] = sum_t r^(63-t) u[64k+t]
        #pragma unroll
        for (int ct=0; ct<2; ++ct){
            f32x4 ar = {0.f,0.f,0.f,0.f}, ai2 = {0.f,0.f,0.f,0.f};
            #pragma unroll
            for (int kh=0; kh<2; ++kh){
                ar  = __builtin_amdgcn_mfma_f32_16x16x32_bf16(Wre[kh], Uh[ct][kh], ar, 0,0,0);
                ar  = __builtin_amdgcn_mfma_f32_16x16x32_bf16(Wre[kh], Ul[ct][kh], ar, 0,0,0);
                ai2 = __builtin_amdgcn_mfma_f32_16x16x32_bf16(Wim[kh], Uh[ct][kh], ai2, 0,0,0);
                ai2 = __builtin_amdgcn_mfma_f32_16x16x32_bf16(Wim[kh], Ul[ct][kh], ai2, 0,0,0);
            }
            const int ch = ct*16 + l15;
            const int n0 = wv*16 + oct*4;
            *(float4*)&w_s[0][ch][n0] = *(float4*)&ar;
            *(float4*)&w_s[1][ch][n0] = *(float4*)&ai2;
        }
        __syncthreads();
        // phase B: scan over chunks (wave 0, lane = n)
        if (wv == 0){
            float sr = 0.0f, si = 0.0f;
            #pragma unroll 4
            for (int k=0;k<NCHK;++k){
                S_s[0][k][lane] = sr; S_s[1][k][lane] = si;   // store S[k-1]
                const float wr = w_s[0][k][lane];
                const float wi = w_s[1][k][lane];
                const float t2 = rhor*sr - rhoi*si + wr;
                si = rhor*si + rhoi*sr + wi;
                sr = t2;
            }
        }
        __syncthreads();
        // phase C: y[j,k] = Re(M S[k-1]) + T u + D u
        #pragma unroll
        for (int ct=0; ct<2; ++ct){
            const int ch = ct*16 + l15;
            bf16x8 Srh[2], Srl[2], Sih[2], Sil[2];
            #pragma unroll
            for (int kh=0; kh<2; ++kh){
                {
                    const float4 x0 = *(const float4*)&S_s[0][ch][kh*32+oct*8];
                    const float4 x1 = *(const float4*)&S_s[0][ch][kh*32+oct*8+4];
                    const float f[8] = {x0.x,x0.y,x0.z,x0.w,x1.x,x1.y,x1.z,x1.w};
                    #pragma unroll
                    for (int i=0;i<8;++i){
                        const short hi = f2bf(f[i]);
                        Srh[kh][i] = hi;
                        Srl[kh][i] = f2bf(f[i] - bf2f(hi));
                    }
                }
                {
                    const float4 x0 = *(const float4*)&S_s[1][ch][kh*32+oct*8];
                    const float4 x1 = *(const float4*)&S_s[1][ch][kh*32+oct*8+4];
                    const float f[8] = {x0.x,x0.y,x0.z,x0.w,x1.x,x1.y,x1.z,x1.w};
                    #pragma unroll
                    for (int i=0;i<8;++i){
                        const short hi = f2bf(f[i]);
                        Sih[kh][i] = hi;
                        Sil[kh][i] = f2bf(f[i] - bf2f(hi));
                    }
                }
            }
            f32x4 acc = {0.f,0.f,0.f,0.f};
            #pragma unroll
            for (int kh=0; kh<2; ++kh){
                acc = __builtin_amdgcn_mfma_f32_16x16x32_bf16(Mre[kh], Srh[kh], acc, 0,0,0);
                acc = __builtin_amdgcn_mfma_f32_16x16x32_bf16(Mre[kh], Srl[kh], acc, 0,0,0);
                acc = __builtin_amdgcn_mfma_f32_16x16x32_bf16(Mni[kh], Sih[kh], acc, 0,0,0);
                acc = __builtin_amdgcn_mfma_f32_16x16x32_bf16(Mni[kh], Sil[kh], acc, 0,0,0);
                acc = __builtin_amdgcn_mfma_f32_16x16x32_bf16(Tf[kh],  Uh[ct][kh], acc, 0,0,0);
                acc = __builtin_amdgcn_mfma_f32_16x16x32_bf16(Tf[kh],  Ul[ct][kh], acc, 0,0,0);
            }
            const int j0 = wv*16 + oct*4;
            const float4 uu = *(const float4*)&u_s[buf][ch][j0];
            float4 y;
            y.x = acc[0] + Dh*uu.x;
            y.y = acc[1] + Dh*uu.y;
            y.z = acc[2] + Dh*uu.z;
            y.w = acc[3] + Dh*uu.w;
            *(float4*)(out + obase + (size_t)(ch*64 + j0)) = y;
        }
        // commit prefetched u into the other buffer
        if (pf){
            const int ch = (tid*8) >> 6, t0 = (tid*8) & 63;
            *(float4*)&u_s[buf^1][ch][t0]   = p0;
            *(float4*)&u_s[buf^1][ch][t0+4] = p1;
        }
        __syncthreads();
    }
}

extern "C" void kernel_launch(void* const* d_in, const int* in_sizes, int n_in,
                              void* d_out, int out_size, void* d_ws, size_t ws_size,
                              hipStream_t stream) {
    const float* u        = (const float*)d_in[0];
    const float* A_re     = (const float*)d_in[1];
    const float* A_im     = (const float*)d_in[2];
    const float* C        = (const float*)d_in[3];
    const float* Dp       = (const float*)d_in[4];
    const float* log_step = (const float*)d_in[5];
    float* out = (float*)d_out;

    const int H = in_sizes[4];                 // 512
    const int L = 2048;                        // fixed by problem
    const int B = in_sizes[0] / (H * L);       // 8
    (void)d_ws; (void)ws_size; (void)out_size; (void)n_in;

    dim3 grid(H);
    dim3 block(256);
    hipLaunchKernelGGL(s4d_mfma, grid, block, 0, stream,
                       u, A_re, A_im, C, Dp, log_step, out, B, H, L);
}